// Round 2
// baseline (500.396 us; speedup 1.0000x reference)
//
#include <hip/hip_runtime.h>
#include <math.h>

// ---------- types ----------
typedef __attribute__((ext_vector_type(8))) short short8;
typedef __attribute__((ext_vector_type(8))) _Float16 half8;
typedef __attribute__((ext_vector_type(2))) __fp16 fp16x2;
typedef __attribute__((ext_vector_type(4))) float float4v;

__device__ __forceinline__ unsigned short f2bf(float f) {
  union { unsigned int i; float f; } x; x.f = f;
  unsigned int r = x.i + 0x7fffu + ((x.i >> 16) & 1u);  // round-nearest-even
  return (unsigned short)(r >> 16);
}

// ---------- LayerNorm: one block per row of 768 ----------
__global__ void ln_kernel(const float* __restrict__ in, const float* __restrict__ g,
                          const float* __restrict__ b, unsigned short* __restrict__ out) {
  const int row = blockIdx.x, t = threadIdx.x;
  const float* xr = in + (size_t)row * 768;
  float v0 = xr[t], v1 = xr[t + 256], v2 = xr[t + 512];
  float s = v0 + v1 + v2;
  float s2 = v0 * v0 + v1 * v1 + v2 * v2;
  for (int off = 32; off > 0; off >>= 1) {
    s += __shfl_xor(s, off, 64);
    s2 += __shfl_xor(s2, off, 64);
  }
  __shared__ float red[8];
  const int wave = t >> 6, lane = t & 63;
  if (lane == 0) { red[wave] = s; red[wave + 4] = s2; }
  __syncthreads();
  s = red[0] + red[1] + red[2] + red[3];
  s2 = red[4] + red[5] + red[6] + red[7];
  const float mu = s * (1.0f / 768.0f);
  const float var = s2 * (1.0f / 768.0f) - mu * mu;
  const float rstd = rsqrtf(var + 1e-5f);
  unsigned short* orow = out + (size_t)row * 768;
  orow[t]       = f2bf((v0 - mu) * rstd * g[t]       + b[t]);
  orow[t + 256] = f2bf((v1 - mu) * rstd * g[t + 256] + b[t + 256]);
  orow[t + 512] = f2bf((v2 - mu) * rstd * g[t + 512] + b[t + 512]);
}

// ---------- weight transpose+convert: f32 (K,N) -> bf16 (N,K) ----------
__global__ void wtrans_kernel(const float* __restrict__ in, unsigned short* __restrict__ out,
                              int K, int N) {
  __shared__ float tile[32][33];
  const int k0 = blockIdx.y * 32, n0 = blockIdx.x * 32;
  const int tr = threadIdx.x >> 5, tc = threadIdx.x & 31;
#pragma unroll
  for (int i = 0; i < 4; ++i)
    tile[tr + i * 8][tc] = in[(size_t)(k0 + tr + i * 8) * N + n0 + tc];
  __syncthreads();
#pragma unroll
  for (int i = 0; i < 4; ++i)
    out[(size_t)(n0 + tr + i * 8) * K + k0 + tc] = f2bf(tile[tc][tr + i * 8]);
}

// ---------- XCD-aware block swizzle ----------
#define SWIZ_BLOCK(GX, TW)                                        \
  const int _id = (int)blockIdx.x;                                \
  const int _gy8 = (int)gridDim.x / (8 * (GX));                   \
  const int _xcd = _id & 7, _jj = _id >> 3;                       \
  const int row0 = (_xcd * _gy8 + _jj / (GX)) * 128;              \
  const int col0 = (_jj % (GX)) * (TW);

// ---------- GEMM 128x128, BK=64, XOR-swizzled LDS, 2-phase dbuf ----------
__device__ __forceinline__ void stage128(
    const unsigned short* __restrict__ A, int lda,
    const unsigned short* __restrict__ Bt, int ldb,
    int row0, int col0, int kk,
    unsigned short* Asb, unsigned short* Bsb,
    int wave, int srow, int scol) {
#pragma unroll
  for (int j = 0; j < 4; ++j) {
    const int chunk = wave * 4 + j;
    const int r = chunk * 8 + srow;
    __builtin_amdgcn_global_load_lds(
        (const __attribute__((address_space(1))) unsigned int*)(A + (size_t)(row0 + r) * lda + kk + scol),
        (__attribute__((address_space(3))) unsigned int*)(Asb + chunk * 512),
        16, 0, 0);
    __builtin_amdgcn_global_load_lds(
        (const __attribute__((address_space(1))) unsigned int*)(Bt + (size_t)(col0 + r) * ldb + kk + scol),
        (__attribute__((address_space(3))) unsigned int*)(Bsb + chunk * 512),
        16, 0, 0);
  }
}

__device__ __forceinline__ void mfma_step128(
    const unsigned short* Ab, const unsigned short* Bb,
    int wr, int wc, int quad, int l16, float4v acc[4][4]) {
#pragma unroll
  for (int ks = 0; ks < 2; ++ks) {
    const int gsw = ((ks * 4 + quad) ^ (l16 & 7)) * 8;
    short8 af[4], bfv[4];
#pragma unroll
    for (int i = 0; i < 4; ++i) {
      af[i]  = *(const short8*)(Ab + (wr * 64 + i * 16 + l16) * 64 + gsw);
      bfv[i] = *(const short8*)(Bb + (wc * 64 + i * 16 + l16) * 64 + gsw);
    }
#pragma unroll
    for (int mt = 0; mt < 4; ++mt)
#pragma unroll
      for (int nt = 0; nt < 4; ++nt)
        acc[mt][nt] = __builtin_amdgcn_mfma_f32_16x16x32_bf16(af[mt], bfv[nt], acc[mt][nt], 0, 0, 0);
  }
}

// K must be a multiple of 128.
__device__ __forceinline__ void gemm128(
    const unsigned short* __restrict__ A, int lda,
    const unsigned short* __restrict__ Bt, int ldb, int K,
    int row0, int col0,
    unsigned short* As, unsigned short* Bs,
    float4v acc[4][4]) {
  const int t = threadIdx.x, lane = t & 63, wave = t >> 6;
  const int quad = lane >> 4, l16 = lane & 15;
  const int wr = wave >> 1, wc = wave & 1;
  const int srow = lane >> 3;
  const int scol = ((lane & 7) ^ srow) * 8;
#pragma unroll
  for (int mt = 0; mt < 4; ++mt)
#pragma unroll
    for (int nt = 0; nt < 4; ++nt) acc[mt][nt] = (float4v)(0.0f);

  stage128(A, lda, Bt, ldb, row0, col0, 0, As, Bs, wave, srow, scol);
  __syncthreads();
  for (int kk = 0; kk < K; kk += 128) {
    // step A: compute buf0, prefetch kk+64 into buf1
    if (kk + 64 < K)
      stage128(A, lda, Bt, ldb, row0, col0, kk + 64, As + 8192, Bs + 8192, wave, srow, scol);
    mfma_step128(As, Bs, wr, wc, quad, l16, acc);
    __syncthreads();
    // step B: compute buf1, prefetch kk+128 into buf0
    if (kk + 128 < K)
      stage128(A, lda, Bt, ldb, row0, col0, kk + 128, As, Bs, wave, srow, scol);
    mfma_step128(As + 8192, Bs + 8192, wr, wc, quad, l16, acc);
    __syncthreads();
  }
}

#define GEMM128_PROLOGUE(GX)                                     \
  __shared__ unsigned short As[2 * 128 * 64];                    \
  __shared__ unsigned short Bs[2 * 128 * 64];                    \
  float4v acc[4][4];                                             \
  SWIZ_BLOCK(GX, 128)                                            \
  const int t = threadIdx.x, lane = t & 63, wave = t >> 6;       \
  const int quad = lane >> 4, l16 = lane & 15;                   \
  const int wr = wave >> 1, wc = wave & 1; (void)t;

// ---------- GEMM 128x64, BK=64, XOR-swizzled LDS, 2-phase dbuf ----------
__device__ __forceinline__ void stage12864(
    const unsigned short* __restrict__ A, int lda,
    const unsigned short* __restrict__ Bt, int ldb,
    int row0, int col0, int kk,
    unsigned short* Asb, unsigned short* Bsb,
    int wave, int srow, int scol) {
#pragma unroll
  for (int j = 0; j < 4; ++j) {
    const int chunk = wave * 4 + j;
    const int r = chunk * 8 + srow;
    __builtin_amdgcn_global_load_lds(
        (const __attribute__((address_space(1))) unsigned int*)(A + (size_t)(row0 + r) * lda + kk + scol),
        (__attribute__((address_space(3))) unsigned int*)(Asb + chunk * 512),
        16, 0, 0);
  }
#pragma unroll
  for (int j = 0; j < 2; ++j) {
    const int chunk = wave * 2 + j;
    const int r = chunk * 8 + srow;
    __builtin_amdgcn_global_load_lds(
        (const __attribute__((address_space(1))) unsigned int*)(Bt + (size_t)(col0 + r) * ldb + kk + scol),
        (__attribute__((address_space(3))) unsigned int*)(Bsb + chunk * 512),
        16, 0, 0);
  }
}

__device__ __forceinline__ void mfma_step12864(
    const unsigned short* Ab, const unsigned short* Bb,
    int wave, int quad, int l16, float4v acc[2][4]) {
#pragma unroll
  for (int ks = 0; ks < 2; ++ks) {
    const int gsw = ((ks * 4 + quad) ^ (l16 & 7)) * 8;
    short8 af[2], bfv[4];
#pragma unroll
    for (int i = 0; i < 2; ++i)
      af[i] = *(const short8*)(Ab + (wave * 32 + i * 16 + l16) * 64 + gsw);
#pragma unroll
    for (int i = 0; i < 4; ++i)
      bfv[i] = *(const short8*)(Bb + (i * 16 + l16) * 64 + gsw);
#pragma unroll
    for (int mt = 0; mt < 2; ++mt)
#pragma unroll
      for (int nt = 0; nt < 4; ++nt)
        acc[mt][nt] = __builtin_amdgcn_mfma_f32_16x16x32_bf16(af[mt], bfv[nt], acc[mt][nt], 0, 0, 0);
  }
}

// K must be a multiple of 128.
__device__ __forceinline__ void gemm12864(
    const unsigned short* __restrict__ A, int lda,
    const unsigned short* __restrict__ Bt, int ldb, int K,
    int row0, int col0,
    unsigned short* As, unsigned short* Bs,
    float4v acc[2][4]) {
  const int t = threadIdx.x, lane = t & 63, wave = t >> 6;
  const int quad = lane >> 4, l16 = lane & 15;
  const int srow = lane >> 3;
  const int scol = ((lane & 7) ^ srow) * 8;
#pragma unroll
  for (int mt = 0; mt < 2; ++mt)
#pragma unroll
    for (int nt = 0; nt < 4; ++nt) acc[mt][nt] = (float4v)(0.0f);

  stage12864(A, lda, Bt, ldb, row0, col0, 0, As, Bs, wave, srow, scol);
  __syncthreads();
  for (int kk = 0; kk < K; kk += 128) {
    if (kk + 64 < K)
      stage12864(A, lda, Bt, ldb, row0, col0, kk + 64, As + 8192, Bs + 4096, wave, srow, scol);
    mfma_step12864(As, Bs, wave, quad, l16, acc);
    __syncthreads();
    if (kk + 128 < K)
      stage12864(A, lda, Bt, ldb, row0, col0, kk + 128, As, Bs, wave, srow, scol);
    mfma_step12864(As + 8192, Bs + 4096, wave, quad, l16, acc);
    __syncthreads();
  }
}

#define GEMM12864_PROLOGUE(GX)                                   \
  __shared__ unsigned short As[2 * 128 * 64];                    \
  __shared__ unsigned short Bs[2 * 64 * 64];                     \
  float4v acc[2][4];                                             \
  SWIZ_BLOCK(GX, 64)                                             \
  const int t = threadIdx.x, lane = t & 63, wave = t >> 6;       \
  const int quad = lane >> 4, l16 = lane & 15; (void)t;

// ---------- kv GEMM: xn @ w_kv -> k (B,H,N,DH) f16, v^T (B,H,DH,N) f16 ----------
__global__ void gemm_kv_kernel(const unsigned short* __restrict__ xn,
                               const unsigned short* __restrict__ wkvt,
                               _Float16* __restrict__ kbuf,
                               _Float16* __restrict__ vtbuf) {
  GEMM128_PROLOGUE(12)
  gemm128(xn, 768, wkvt, 768, 768, row0, col0, As, Bs, acc);
#pragma unroll
  for (int mt = 0; mt < 4; ++mt)
#pragma unroll
    for (int nt = 0; nt < 4; ++nt) {
      const int j = col0 + wc * 64 + nt * 16 + l16;
#pragma unroll
      for (int r = 0; r < 4; ++r) {
        const int m = row0 + wr * 64 + mt * 16 + quad * 4 + r;
        const int bb = m >> 10, n = m & 1023;
        const float c = acc[mt][nt][r];
        if (j < 768) {
          const int hh = j >> 6, d = j & 63;
          kbuf[((size_t)(bb * 12 + hh) * 1024 + n) * 64 + d] = (_Float16)c;
        } else {
          const int j2 = j - 768, hh = j2 >> 6, d = j2 & 63;
          vtbuf[((size_t)(bb * 12 + hh) * 64 + d) * 1024 + n] = (_Float16)c;
        }
      }
    }
}

// ---------- MFMA flash attention, f16 ----------
// 768 blocks, 1D: id = qb*96 + (h*8+b); id%8 = b -> all q-blocks of one (b,h)
// (and all heads of one batch) share an XCD -> K/V stays in that XCD's L2.
// Block = 128 q rows, 4 waves x 32 q rows (two 16-row q-sets per wave).
// Key chunks of 64 staged in LDS, register prefetch of chunk c+1 overlaps
// compute. exp2-domain softmax: Q pre-scaled by 0.125*log2(e) so exp() is a
// bare v_exp_f32. Defer-rescale (THR=8 in log2 domain): skip the O-rescale +
// alpha broadcast when no q-row's chunk max exceeds the running max by >8;
// P is then bounded by 2^8=256, well inside f16 range.
#define AST 72
#define PST 72
__global__ __launch_bounds__(256, 3)
void attn_kernel(const float* __restrict__ q_extra,
                 const _Float16* __restrict__ kbuf,
                 const _Float16* __restrict__ vtbuf,
                 unsigned short* __restrict__ ao) {
  __shared__ _Float16 Ks[64 * AST];
  __shared__ _Float16 Vs[64 * AST];
  __shared__ _Float16 Ps[4][2][16 * PST];
  const int id = (int)blockIdx.x;
  const int pair = id % 96, qb = id / 96;
  const int h = pair >> 3, b = pair & 7;
  const int q0 = qb * 128;
  const int t = threadIdx.x, lane = t & 63, wave = t >> 6;
  const int quad = lane >> 4, l16 = lane & 15;

  // Q fragments (B-operand layout) f16, pre-scaled by 0.125*log2(e)
  const float QS = 0.125f * 1.44269504088896f;
  half8 qf[2][2];
#pragma unroll
  for (int qs = 0; qs < 2; ++qs) {
    const float* qp = q_extra +
        ((size_t)((b * 1024 + q0 + wave * 32 + qs * 16 + l16) * 12 + h)) * 64 + quad * 8;
    float4 a0 = *(const float4*)(qp);
    float4 a1 = *(const float4*)(qp + 4);
    float4 c0 = *(const float4*)(qp + 32);
    float4 c1 = *(const float4*)(qp + 36);
    union { fp16x2 h2[4]; half8 h8; } u0, u1;
    u0.h2[0] = __builtin_amdgcn_cvt_pkrtz(a0.x * QS, a0.y * QS);
    u0.h2[1] = __builtin_amdgcn_cvt_pkrtz(a0.z * QS, a0.w * QS);
    u0.h2[2] = __builtin_amdgcn_cvt_pkrtz(a1.x * QS, a1.y * QS);
    u0.h2[3] = __builtin_amdgcn_cvt_pkrtz(a1.z * QS, a1.w * QS);
    u1.h2[0] = __builtin_amdgcn_cvt_pkrtz(c0.x * QS, c0.y * QS);
    u1.h2[1] = __builtin_amdgcn_cvt_pkrtz(c0.z * QS, c0.w * QS);
    u1.h2[2] = __builtin_amdgcn_cvt_pkrtz(c1.x * QS, c1.y * QS);
    u1.h2[3] = __builtin_amdgcn_cvt_pkrtz(c1.z * QS, c1.w * QS);
    qf[qs][0] = u0.h8; qf[qs][1] = u1.h8;
  }

  const _Float16* kb = kbuf + (size_t)(b * 12 + h) * 65536;
  const _Float16* vb = vtbuf + (size_t)(b * 12 + h) * 65536;
  const int srow = t >> 2, su = (t & 3) * 16;

  // prefetch chunk 0
  half8 kp0 = *(const half8*)(kb + (size_t)srow * 64 + su);
  half8 kp1 = *(const half8*)(kb + (size_t)srow * 64 + su + 8);
  half8 vp0 = *(const half8*)(vb + (size_t)srow * 1024 + su);
  half8 vp1 = *(const half8*)(vb + (size_t)srow * 1024 + su + 8);

  float m_s[2] = {-1e30f, -1e30f}, l_s[2] = {0.0f, 0.0f};
  float4v acc[2][4];
#pragma unroll
  for (int qs = 0; qs < 2; ++qs)
#pragma unroll
    for (int nt = 0; nt < 4; ++nt) acc[qs][nt] = (float4v)(0.0f);

  for (int c = 0; c < 16; ++c) {
    __syncthreads();
    *(half8*)(Ks + srow * AST + su)     = kp0;
    *(half8*)(Ks + srow * AST + su + 8) = kp1;
    *(half8*)(Vs + srow * AST + su)     = vp0;
    *(half8*)(Vs + srow * AST + su + 8) = vp1;
    if (c < 15) {
      const int key1 = (c + 1) * 64;
      kp0 = *(const half8*)(kb + (size_t)(key1 + srow) * 64 + su);
      kp1 = *(const half8*)(kb + (size_t)(key1 + srow) * 64 + su + 8);
      vp0 = *(const half8*)(vb + (size_t)srow * 1024 + key1 + su);
      vp1 = *(const half8*)(vb + (size_t)srow * 1024 + key1 + su + 8);
    }
    __syncthreads();

#pragma unroll
    for (int qs = 0; qs < 2; ++qs) {
      // S^T = K @ Q^T (log2-domain scores)
      float4v s[4];
#pragma unroll
      for (int kt = 0; kt < 4; ++kt) {
        const _Float16* kr = Ks + (kt * 16 + l16) * AST;
        half8 kf0 = *(const half8*)(kr + quad * 8);
        half8 kf1 = *(const half8*)(kr + 32 + quad * 8);
        float4v a = (float4v)(0.f);
        a = __builtin_amdgcn_mfma_f32_16x16x32_f16(kf0, qf[qs][0], a, 0, 0, 0);
        a = __builtin_amdgcn_mfma_f32_16x16x32_f16(kf1, qf[qs][1], a, 0, 0, 0);
        s[kt] = a;
      }

      // per-lane online softmax (base-2) for q = l16
      float mx = fmaxf(fmaxf(fmaxf(s[0][0], s[0][1]), fmaxf(s[0][2], s[0][3])),
                       fmaxf(fmaxf(s[1][0], s[1][1]), fmaxf(s[1][2], s[1][3])));
      mx = fmaxf(mx, fmaxf(fmaxf(fmaxf(s[2][0], s[2][1]), fmaxf(s[2][2], s[2][3])),
                           fmaxf(fmaxf(s[3][0], s[3][1]), fmaxf(s[3][2], s[3][3]))));
      mx = fmaxf(mx, __shfl_xor(mx, 16, 64));
      mx = fmaxf(mx, __shfl_xor(mx, 32, 64));

      // defer-rescale: only rescale when some q-row's max grew by > 8 (log2)
      if (!__all(mx <= m_s[qs] + 8.0f)) {
        const float mn = fmaxf(m_s[qs], mx);
        const float alpha = exp2f(m_s[qs] - mn);
        m_s[qs] = mn;
        l_s[qs] *= alpha;
        float ab[4];
#pragma unroll
        for (int r = 0; r < 4; ++r) ab[r] = __shfl(alpha, quad * 4 + r, 64);
#pragma unroll
        for (int nt = 0; nt < 4; ++nt)
#pragma unroll
          for (int r = 0; r < 4; ++r) acc[qs][nt][r] *= ab[r];
      }

      _Float16* pw = Ps[wave][qs];
      float sum = 0.0f;
#pragma unroll
      for (int kt = 0; kt < 4; ++kt) {
        const float p0 = exp2f(s[kt][0] - m_s[qs]);
        const float p1 = exp2f(s[kt][1] - m_s[qs]);
        const float p2 = exp2f(s[kt][2] - m_s[qs]);
        const float p3 = exp2f(s[kt][3] - m_s[qs]);
        sum += (p0 + p1) + (p2 + p3);
        union { fp16x2 h2[2]; uint2 u; } pk;
        pk.h2[0] = __builtin_amdgcn_cvt_pkrtz(p0, p1);
        pk.h2[1] = __builtin_amdgcn_cvt_pkrtz(p2, p3);
        *(uint2*)(pw + l16 * PST + kt * 16 + quad * 4) = pk.u;
      }
      sum += __shfl_xor(sum, 16, 64);
      sum += __shfl_xor(sum, 32, 64);
      l_s[qs] += sum;

      // O += P @ V
      half8 pf0 = *(const half8*)(pw + l16 * PST + quad * 8);
      half8 pf1 = *(const half8*)(pw + l16 * PST + 32 + quad * 8);
#pragma unroll
      for (int nt = 0; nt < 4; ++nt) {
        const _Float16* vr = Vs + (nt * 16 + l16) * AST;
        half8 vf0 = *(const half8*)(vr + quad * 8);
        half8 vf1 = *(const half8*)(vr + 32 + quad * 8);
        acc[qs][nt] = __builtin_amdgcn_mfma_f32_16x16x32_f16(pf0, vf0, acc[qs][nt], 0, 0, 0);
        acc[qs][nt] = __builtin_amdgcn_mfma_f32_16x16x32_f16(pf1, vf1, acc[qs][nt], 0, 0, 0);
      }
    }
  }

#pragma unroll
  for (int qs = 0; qs < 2; ++qs) {
    const float inv = 1.0f / l_s[qs];
    float ib[4];
#pragma unroll
    for (int r = 0; r < 4; ++r) ib[r] = __shfl(inv, quad * 4 + r, 64);
#pragma unroll
    for (int nt = 0; nt < 4; ++nt) {
#pragma unroll
      for (int r = 0; r < 4; ++r) {
        const int m = q0 + wave * 32 + qs * 16 + quad * 4 + r;
        ao[(size_t)(b * 1024 + m) * 768 + h * 64 + nt * 16 + l16] =
            f2bf(acc[qs][nt][r] * ib[r]);
      }
    }
  }
}

// ---------- out-proj GEMM + bias + residual -> x2 (f32), 128x64 tiles ----------
__global__ void gemm_outproj_kernel(const unsigned short* __restrict__ ao,
                                    const unsigned short* __restrict__ woutt,
                                    const float* __restrict__ b_out,
                                    const float* __restrict__ x,
                                    float* __restrict__ x2) {
  GEMM12864_PROLOGUE(12)
  gemm12864(ao, 768, woutt, 768, 768, row0, col0, As, Bs, acc);
#pragma unroll
  for (int mt = 0; mt < 2; ++mt)
#pragma unroll
    for (int nt = 0; nt < 4; ++nt) {
      const int j = col0 + nt * 16 + l16;
#pragma unroll
      for (int r = 0; r < 4; ++r) {
        const int m = row0 + wave * 32 + mt * 16 + quad * 4 + r;
        const size_t idx = (size_t)m * 768 + j;
        x2[idx] = acc[mt][nt][r] + b_out[j] + x[idx];
      }
    }
}

// ---------- MLP1 GEMM + bias + exact GELU -> h1 (bf16), 128x128 ----------
__global__ void gemm_mlp1_kernel(const unsigned short* __restrict__ h,
                                 const unsigned short* __restrict__ w1t,
                                 const float* __restrict__ b1,
                                 unsigned short* __restrict__ h1) {
  GEMM128_PROLOGUE(24)
  gemm128(h, 768, w1t, 768, 768, row0, col0, As, Bs, acc);
#pragma unroll
  for (int mt = 0; mt < 4; ++mt)
#pragma unroll
    for (int nt = 0; nt < 4; ++nt) {
      const int j = col0 + wc * 64 + nt * 16 + l16;
#pragma unroll
      for (int r = 0; r < 4; ++r) {
        const int m = row0 + wr * 64 + mt * 16 + quad * 4 + r;
        const float y = acc[mt][nt][r] + b1[j];
        const float ge = 0.5f * y * (1.0f + erff(y * 0.70710678118654752f));
        h1[(size_t)m * 3072 + j] = f2bf(ge);
      }
    }
}

// ---------- MLP2 GEMM + bias + residual -> out (f32), 128x64 tiles ----------
__global__ void gemm_mlp2_kernel(const unsigned short* __restrict__ h1,
                                 const unsigned short* __restrict__ w2t,
                                 const float* __restrict__ b2,
                                 const float* __restrict__ x2,
                                 float* __restrict__ out) {
  GEMM12864_PROLOGUE(12)
  gemm12864(h1, 3072, w2t, 3072, 3072, row0, col0, As, Bs, acc);
#pragma unroll
  for (int mt = 0; mt < 2; ++mt)
#pragma unroll
    for (int nt = 0; nt < 4; ++nt) {
      const int j = col0 + nt * 16 + l16;
#pragma unroll
      for (int r = 0; r < 4; ++r) {
        const int m = row0 + wave * 32 + mt * 16 + quad * 4 + r;
        const size_t idx = (size_t)m * 768 + j;
        out[idx] = acc[mt][nt][r] + b2[j] + x2[idx];
      }
    }
}

// ---------- launch ----------
extern "C" void kernel_launch(void* const* d_in, const int* in_sizes, int n_in,
                              void* d_out, int out_size, void* d_ws, size_t ws_size,
                              hipStream_t stream) {
  const float* x       = (const float*)d_in[0];
  const float* q_extra = (const float*)d_in[1];
  const float* ln1_g   = (const float*)d_in[2];
  const float* ln1_b   = (const float*)d_in[3];
  const float* w_kv    = (const float*)d_in[4];
  const float* w_out   = (const float*)d_in[5];
  const float* b_out   = (const float*)d_in[6];
  const float* ln2_g   = (const float*)d_in[7];
  const float* ln2_b   = (const float*)d_in[8];
  const float* w1      = (const float*)d_in[9];
  const float* b1      = (const float*)d_in[10];
  const float* w2      = (const float*)d_in[11];
  const float* b2      = (const float*)d_in[12];
  float* out = (float*)d_out;

  char* ws = (char*)d_ws;
  unsigned short* xn    = (unsigned short*)(ws);
  _Float16*       kbuf  = (_Float16*)(ws + 12582912);
  _Float16*       vtbuf = (_Float16*)(ws + 25165824);
  unsigned short* ao    = (unsigned short*)(ws + 37748736);
  float*          x2    = (float*)(ws + 50331648);
  unsigned short* h1    = (unsigned short*)(ws + 75497472);
  unsigned short* hbuf  = xn;   // xn dead after kv GEMM
  unsigned short* wkvt  = ao;                          // dead before attn writes ao
  unsigned short* woutt = h1;                          // dead before mlp1 writes h1
  unsigned short* w1t   = (unsigned short*)kbuf;       // kbuf dead after attn
  unsigned short* w2t   = (unsigned short*)vtbuf;      // vtbuf dead after attn

  ln_kernel<<<8192, 256, 0, stream>>>(x, ln1_g, ln1_b, xn);
  wtrans_kernel<<<dim3(48, 24), 256, 0, stream>>>(w_kv, wkvt, 768, 1536);
  wtrans_kernel<<<dim3(24, 24), 256, 0, stream>>>(w_out, woutt, 768, 768);
  gemm_kv_kernel<<<768, 256, 0, stream>>>(xn, wkvt, kbuf, vtbuf);
  attn_kernel<<<768, 256, 0, stream>>>(q_extra, kbuf, vtbuf, ao);
  wtrans_kernel<<<dim3(96, 24), 256, 0, stream>>>(w1, w1t, 768, 3072);
  wtrans_kernel<<<dim3(24, 96), 256, 0, stream>>>(w2, w2t, 3072, 768);
  gemm_outproj_kernel<<<768, 256, 0, stream>>>(ao, woutt, b_out, x, x2);
  ln_kernel<<<8192, 256, 0, stream>>>(x2, ln2_g, ln2_b, hbuf);
  gemm_mlp1_kernel<<<1536, 256, 0, stream>>>(hbuf, w1t, b1, h1);
  gemm_mlp2_kernel<<<768, 256, 0, stream>>>(h1, w2t, b2, x2, out);
}

// Round 3
// 354.354 us; speedup vs baseline: 1.4121x; 1.4121x over previous
//
#include <hip/hip_runtime.h>
#include <math.h>

// ---------- types ----------
typedef __attribute__((ext_vector_type(8))) short short8;
typedef __attribute__((ext_vector_type(8))) _Float16 half8;
typedef __attribute__((ext_vector_type(2))) __fp16 fp16x2;
typedef __attribute__((ext_vector_type(4))) float float4v;
typedef __attribute__((ext_vector_type(4))) unsigned short ushort4v;

__device__ __forceinline__ unsigned short f2bf(float f) {
  union { unsigned int i; float f; } x; x.f = f;
  unsigned int r = x.i + 0x7fffu + ((x.i >> 16) & 1u);  // round-nearest-even
  return (unsigned short)(r >> 16);
}

// branch-free exact-GELU via Abramowitz-Stegun 7.1.26 (|erf err| <= 1.5e-7)
__device__ __forceinline__ float gelu_f(float y) {
  const float z = fabsf(y) * 0.70710678118654752f;
  const float t = 1.0f / (1.0f + 0.3275911f * z);
  const float poly = t * (0.254829592f + t * (-0.284496736f +
                     t * (1.421413741f + t * (-1.453152027f + t * 1.061405429f))));
  const float e = exp2f(-z * z * 1.44269504088896f);
  const float erfz = copysignf(1.0f - poly * e, y);
  return 0.5f * y * (1.0f + erfz);
}

// ---------- LayerNorm: one ROW per WAVE (no LDS, no barrier) ----------
__global__ void ln_kernel(const float* __restrict__ in, const float* __restrict__ g,
                          const float* __restrict__ b, unsigned short* __restrict__ out) {
  const int wave = threadIdx.x >> 6, lane = threadIdx.x & 63;
  const int row = blockIdx.x * 4 + wave;
  const float* xr = in + (size_t)row * 768 + lane * 4;
  const float4 v0 = *(const float4*)(xr);
  const float4 v1 = *(const float4*)(xr + 256);
  const float4 v2 = *(const float4*)(xr + 512);
  float s  = (v0.x + v0.y) + (v0.z + v0.w) + (v1.x + v1.y) + (v1.z + v1.w)
           + (v2.x + v2.y) + (v2.z + v2.w);
  float s2 = v0.x*v0.x + v0.y*v0.y + v0.z*v0.z + v0.w*v0.w
           + v1.x*v1.x + v1.y*v1.y + v1.z*v1.z + v1.w*v1.w
           + v2.x*v2.x + v2.y*v2.y + v2.z*v2.z + v2.w*v2.w;
  for (int off = 32; off > 0; off >>= 1) {
    s  += __shfl_xor(s, off, 64);
    s2 += __shfl_xor(s2, off, 64);
  }
  const float mu = s * (1.0f / 768.0f);
  const float var = s2 * (1.0f / 768.0f) - mu * mu;
  const float rstd = rsqrtf(var + 1e-5f);
  const float* gp = g + lane * 4;
  const float* bp = b + lane * 4;
  unsigned short* orow = out + (size_t)row * 768 + lane * 4;
#pragma unroll
  for (int k = 0; k < 3; ++k) {
    const float4 v = (k == 0) ? v0 : (k == 1) ? v1 : v2;
    const float4 gv = *(const float4*)(gp + k * 256);
    const float4 bv = *(const float4*)(bp + k * 256);
    ushort4v o;
    o.x = f2bf((v.x - mu) * rstd * gv.x + bv.x);
    o.y = f2bf((v.y - mu) * rstd * gv.y + bv.y);
    o.z = f2bf((v.z - mu) * rstd * gv.z + bv.z);
    o.w = f2bf((v.w - mu) * rstd * gv.w + bv.w);
    *(ushort4v*)(orow + k * 256) = o;
  }
}

// ---------- weight transpose+convert: f32 (K,N) -> bf16 (N,K) ----------
__global__ void wtrans_kernel(const float* __restrict__ in, unsigned short* __restrict__ out,
                              int K, int N) {
  __shared__ float tile[32][33];
  const int k0 = blockIdx.y * 32, n0 = blockIdx.x * 32;
  const int tr = threadIdx.x >> 5, tc = threadIdx.x & 31;
#pragma unroll
  for (int i = 0; i < 4; ++i)
    tile[tr + i * 8][tc] = in[(size_t)(k0 + tr + i * 8) * N + n0 + tc];
  __syncthreads();
#pragma unroll
  for (int i = 0; i < 4; ++i)
    out[(size_t)(n0 + tr + i * 8) * K + k0 + tc] = f2bf(tile[tc][tr + i * 8]);
}

// ---------- XCD-aware block swizzle ----------
#define SWIZ_BLOCK(GX, TW)                                        \
  const int _id = (int)blockIdx.x;                                \
  const int _gy8 = (int)gridDim.x / (8 * (GX));                   \
  const int _xcd = _id & 7, _jj = _id >> 3;                       \
  const int row0 = (_xcd * _gy8 + _jj / (GX)) * 128;              \
  const int col0 = (_jj % (GX)) * (TW);

#define ASM_FENCE asm volatile("" ::: "memory")

// ---------- GEMM core 128x128, BK=64, XOR-swizzled LDS (single-buffer) ----------
__device__ __forceinline__ void gemm128(
    const unsigned short* __restrict__ A, int lda,
    const unsigned short* __restrict__ Bt, int ldb, int K,
    int row0, int col0,
    unsigned short* As, unsigned short* Bs,
    float4v acc[4][4]) {
  const int t = threadIdx.x, lane = t & 63, wave = t >> 6;
  const int quad = lane >> 4, l16 = lane & 15;
  const int wr = wave >> 1, wc = wave & 1;
  const int srow = lane >> 3;
  const int scol = ((lane & 7) ^ srow) * 8;
#pragma unroll
  for (int mt = 0; mt < 4; ++mt)
#pragma unroll
    for (int nt = 0; nt < 4; ++nt) acc[mt][nt] = (float4v)(0.0f);

  for (int kk = 0; kk < K; kk += 64) {
    __syncthreads();
#pragma unroll
    for (int j = 0; j < 4; ++j) {
      const int chunk = wave * 4 + j;
      const int r = chunk * 8 + srow;
      __builtin_amdgcn_global_load_lds(
          (const __attribute__((address_space(1))) unsigned int*)(A + (size_t)(row0 + r) * lda + kk + scol),
          (__attribute__((address_space(3))) unsigned int*)(As + chunk * 512),
          16, 0, 0);
      __builtin_amdgcn_global_load_lds(
          (const __attribute__((address_space(1))) unsigned int*)(Bt + (size_t)(col0 + r) * ldb + kk + scol),
          (__attribute__((address_space(3))) unsigned int*)(Bs + chunk * 512),
          16, 0, 0);
    }
    __syncthreads();
#pragma unroll
    for (int ks = 0; ks < 2; ++ks) {
      const int gsw = ((ks * 4 + quad) ^ (l16 & 7)) * 8;
      short8 af[4], bfv[4];
#pragma unroll
      for (int i = 0; i < 4; ++i) {
        af[i]  = *(const short8*)(As + (wr * 64 + i * 16 + l16) * 64 + gsw);
        bfv[i] = *(const short8*)(Bs + (wc * 64 + i * 16 + l16) * 64 + gsw);
      }
#pragma unroll
      for (int mt = 0; mt < 4; ++mt)
#pragma unroll
        for (int nt = 0; nt < 4; ++nt)
          acc[mt][nt] = __builtin_amdgcn_mfma_f32_16x16x32_bf16(af[mt], bfv[nt], acc[mt][nt], 0, 0, 0);
    }
  }
}

#define GEMM128_PROLOGUE(GX)                                     \
  __shared__ unsigned short As[128 * 64];                        \
  __shared__ unsigned short Bs[128 * 64];                        \
  float4v acc[4][4];                                             \
  SWIZ_BLOCK(GX, 128)                                            \
  const int t = threadIdx.x, lane = t & 63, wave = t >> 6;       \
  const int quad = lane >> 4, l16 = lane & 15;                   \
  const int wr = wave >> 1, wc = wave & 1; (void)t;

// ---------- GEMM core 128x64, BK=64, counted-vmcnt double-buffer ----------
// 48 KB LDS -> 3 blocks/CU, same as the 768-block grid residency: no
// occupancy change vs single-buffer. Raw s_barrier (no vmcnt drain);
// per-wave s_waitcnt vmcnt(6) allows the 6 loads of the NEXT batch to stay
// in flight across the compute of the current batch (T4 counted wait).
__device__ __forceinline__ void stage12864(
    const unsigned short* __restrict__ A, int lda,
    const unsigned short* __restrict__ Bt, int ldb,
    int row0, int col0, int kk,
    unsigned short* Asb, unsigned short* Bsb,
    int wave, int srow, int scol) {
#pragma unroll
  for (int j = 0; j < 4; ++j) {
    const int chunk = wave * 4 + j;
    const int r = chunk * 8 + srow;
    __builtin_amdgcn_global_load_lds(
        (const __attribute__((address_space(1))) unsigned int*)(A + (size_t)(row0 + r) * lda + kk + scol),
        (__attribute__((address_space(3))) unsigned int*)(Asb + chunk * 512),
        16, 0, 0);
  }
#pragma unroll
  for (int j = 0; j < 2; ++j) {
    const int chunk = wave * 2 + j;
    const int r = chunk * 8 + srow;
    __builtin_amdgcn_global_load_lds(
        (const __attribute__((address_space(1))) unsigned int*)(Bt + (size_t)(col0 + r) * ldb + kk + scol),
        (__attribute__((address_space(3))) unsigned int*)(Bsb + chunk * 512),
        16, 0, 0);
  }
}

__device__ __forceinline__ void mfma_step12864(
    const unsigned short* Ab, const unsigned short* Bb,
    int wave, int quad, int l16, float4v acc[2][4]) {
#pragma unroll
  for (int ks = 0; ks < 2; ++ks) {
    const int gsw = ((ks * 4 + quad) ^ (l16 & 7)) * 8;
    short8 af[2], bfv[4];
#pragma unroll
    for (int i = 0; i < 2; ++i)
      af[i] = *(const short8*)(Ab + (wave * 32 + i * 16 + l16) * 64 + gsw);
#pragma unroll
    for (int i = 0; i < 4; ++i)
      bfv[i] = *(const short8*)(Bb + (i * 16 + l16) * 64 + gsw);
#pragma unroll
    for (int mt = 0; mt < 2; ++mt)
#pragma unroll
      for (int nt = 0; nt < 4; ++nt)
        acc[mt][nt] = __builtin_amdgcn_mfma_f32_16x16x32_bf16(af[mt], bfv[nt], acc[mt][nt], 0, 0, 0);
  }
}

// K must be a multiple of 128 and >= 256.
__device__ __forceinline__ void gemm12864(
    const unsigned short* __restrict__ A, int lda,
    const unsigned short* __restrict__ Bt, int ldb, int K,
    int row0, int col0,
    unsigned short* As, unsigned short* Bs,
    float4v acc[2][4]) {
  const int t = threadIdx.x, lane = t & 63, wave = t >> 6;
  const int quad = lane >> 4, l16 = lane & 15;
  const int srow = lane >> 3;
  const int scol = ((lane & 7) ^ srow) * 8;
#pragma unroll
  for (int mt = 0; mt < 2; ++mt)
#pragma unroll
    for (int nt = 0; nt < 4; ++nt) acc[mt][nt] = (float4v)(0.0f);

  // prologue: batches 0 and 1 in flight (6 vmem ops each)
  stage12864(A, lda, Bt, ldb, row0, col0, 0, As, Bs, wave, srow, scol);
  stage12864(A, lda, Bt, ldb, row0, col0, 64, As + 8192, Bs + 4096, wave, srow, scol);

  for (int kk = 0; kk < K - 128; kk += 128) {
    // wait own batch-b0 loads (6 newer = b1 batch may remain in flight)
    asm volatile("s_waitcnt vmcnt(6)" ::: "memory");
    __builtin_amdgcn_s_barrier();
    ASM_FENCE;
    mfma_step12864(As, Bs, wave, quad, l16, acc);
    ASM_FENCE;
    __builtin_amdgcn_s_barrier();   // all waves done reading b0
    ASM_FENCE;
    stage12864(A, lda, Bt, ldb, row0, col0, kk + 128, As, Bs, wave, srow, scol);

    asm volatile("s_waitcnt vmcnt(6)" ::: "memory");
    __builtin_amdgcn_s_barrier();
    ASM_FENCE;
    mfma_step12864(As + 8192, Bs + 4096, wave, quad, l16, acc);
    ASM_FENCE;
    __builtin_amdgcn_s_barrier();   // all waves done reading b1
    ASM_FENCE;
    stage12864(A, lda, Bt, ldb, row0, col0, kk + 192, As + 8192, Bs + 4096, wave, srow, scol);
  }
  // tail: batches NB-2, NB-1 (no further stages)
  asm volatile("s_waitcnt vmcnt(6)" ::: "memory");
  __builtin_amdgcn_s_barrier();
  ASM_FENCE;
  mfma_step12864(As, Bs, wave, quad, l16, acc);
  asm volatile("s_waitcnt vmcnt(0)" ::: "memory");
  __builtin_amdgcn_s_barrier();
  ASM_FENCE;
  mfma_step12864(As + 8192, Bs + 4096, wave, quad, l16, acc);
}

#define GEMM12864_PROLOGUE(GX)                                   \
  __shared__ unsigned short As[2 * 128 * 64];                    \
  __shared__ unsigned short Bs[2 * 64 * 64];                     \
  float4v acc[2][4];                                             \
  SWIZ_BLOCK(GX, 64)                                             \
  const int t = threadIdx.x, lane = t & 63, wave = t >> 6;       \
  const int quad = lane >> 4, l16 = lane & 15; (void)t;

// ---------- kv GEMM: xn @ w_kv -> k (B,H,N,DH) f16, v^T (B,H,DH,N) f16 ----------
__global__ void gemm_kv_kernel(const unsigned short* __restrict__ xn,
                               const unsigned short* __restrict__ wkvt,
                               _Float16* __restrict__ kbuf,
                               _Float16* __restrict__ vtbuf) {
  GEMM128_PROLOGUE(12)
  gemm128(xn, 768, wkvt, 768, 768, row0, col0, As, Bs, acc);
#pragma unroll
  for (int mt = 0; mt < 4; ++mt)
#pragma unroll
    for (int nt = 0; nt < 4; ++nt) {
      const int j = col0 + wc * 64 + nt * 16 + l16;
#pragma unroll
      for (int r = 0; r < 4; ++r) {
        const int m = row0 + wr * 64 + mt * 16 + quad * 4 + r;
        const int bb = m >> 10, n = m & 1023;
        const float c = acc[mt][nt][r];
        if (j < 768) {
          const int hh = j >> 6, d = j & 63;
          kbuf[((size_t)(bb * 12 + hh) * 1024 + n) * 64 + d] = (_Float16)c;
        } else {
          const int j2 = j - 768, hh = j2 >> 6, d = j2 & 63;
          vtbuf[((size_t)(bb * 12 + hh) * 64 + d) * 1024 + n] = (_Float16)c;
        }
      }
    }
}

// ---------- MFMA flash attention, f16 ----------
// 768 blocks, 1D: id = qb*96 + (h*8+b); id%8 = b -> all q-blocks of one (b,h)
// (and all heads of one batch) share an XCD -> K/V stays in that XCD's L2.
// Block = 128 q rows, 4 waves x 32 q rows (two 16-row q-sets per wave).
// Key chunks of 64 staged in LDS, register prefetch of chunk c+1 overlaps
// compute. exp2-domain softmax; defer-rescale THR=8 (log2 domain).
#define AST 72
#define PST 72
__global__ __launch_bounds__(256, 3)
void attn_kernel(const float* __restrict__ q_extra,
                 const _Float16* __restrict__ kbuf,
                 const _Float16* __restrict__ vtbuf,
                 unsigned short* __restrict__ ao) {
  __shared__ _Float16 Ks[64 * AST];
  __shared__ _Float16 Vs[64 * AST];
  __shared__ _Float16 Ps[4][2][16 * PST];
  const int id = (int)blockIdx.x;
  const int pair = id % 96, qb = id / 96;
  const int h = pair >> 3, b = pair & 7;
  const int q0 = qb * 128;
  const int t = threadIdx.x, lane = t & 63, wave = t >> 6;
  const int quad = lane >> 4, l16 = lane & 15;

  // Q fragments (B-operand layout) f16, pre-scaled by 0.125*log2(e)
  const float QS = 0.125f * 1.44269504088896f;
  half8 qf[2][2];
#pragma unroll
  for (int qs = 0; qs < 2; ++qs) {
    const float* qp = q_extra +
        ((size_t)((b * 1024 + q0 + wave * 32 + qs * 16 + l16) * 12 + h)) * 64 + quad * 8;
    float4 a0 = *(const float4*)(qp);
    float4 a1 = *(const float4*)(qp + 4);
    float4 c0 = *(const float4*)(qp + 32);
    float4 c1 = *(const float4*)(qp + 36);
    union { fp16x2 h2[4]; half8 h8; } u0, u1;
    u0.h2[0] = __builtin_amdgcn_cvt_pkrtz(a0.x * QS, a0.y * QS);
    u0.h2[1] = __builtin_amdgcn_cvt_pkrtz(a0.z * QS, a0.w * QS);
    u0.h2[2] = __builtin_amdgcn_cvt_pkrtz(a1.x * QS, a1.y * QS);
    u0.h2[3] = __builtin_amdgcn_cvt_pkrtz(a1.z * QS, a1.w * QS);
    u1.h2[0] = __builtin_amdgcn_cvt_pkrtz(c0.x * QS, c0.y * QS);
    u1.h2[1] = __builtin_amdgcn_cvt_pkrtz(c0.z * QS, c0.w * QS);
    u1.h2[2] = __builtin_amdgcn_cvt_pkrtz(c1.x * QS, c1.y * QS);
    u1.h2[3] = __builtin_amdgcn_cvt_pkrtz(c1.z * QS, c1.w * QS);
    qf[qs][0] = u0.h8; qf[qs][1] = u1.h8;
  }

  const _Float16* kb = kbuf + (size_t)(b * 12 + h) * 65536;
  const _Float16* vb = vtbuf + (size_t)(b * 12 + h) * 65536;
  const int srow = t >> 2, su = (t & 3) * 16;

  // prefetch chunk 0
  half8 kp0 = *(const half8*)(kb + (size_t)srow * 64 + su);
  half8 kp1 = *(const half8*)(kb + (size_t)srow * 64 + su + 8);
  half8 vp0 = *(const half8*)(vb + (size_t)srow * 1024 + su);
  half8 vp1 = *(const half8*)(vb + (size_t)srow * 1024 + su + 8);

  float m_s[2] = {-1e30f, -1e30f}, l_s[2] = {0.0f, 0.0f};
  float4v acc[2][4];
#pragma unroll
  for (int qs = 0; qs < 2; ++qs)
#pragma unroll
    for (int nt = 0; nt < 4; ++nt) acc[qs][nt] = (float4v)(0.0f);

  for (int c = 0; c < 16; ++c) {
    __syncthreads();
    *(half8*)(Ks + srow * AST + su)     = kp0;
    *(half8*)(Ks + srow * AST + su + 8) = kp1;
    *(half8*)(Vs + srow * AST + su)     = vp0;
    *(half8*)(Vs + srow * AST + su + 8) = vp1;
    if (c < 15) {
      const int key1 = (c + 1) * 64;
      kp0 = *(const half8*)(kb + (size_t)(key1 + srow) * 64 + su);
      kp1 = *(const half8*)(kb + (size_t)(key1 + srow) * 64 + su + 8);
      vp0 = *(const half8*)(vb + (size_t)srow * 1024 + key1 + su);
      vp1 = *(const half8*)(vb + (size_t)srow * 1024 + key1 + su + 8);
    }
    __syncthreads();

#pragma unroll
    for (int qs = 0; qs < 2; ++qs) {
      // S^T = K @ Q^T (log2-domain scores)
      float4v s[4];
#pragma unroll
      for (int kt = 0; kt < 4; ++kt) {
        const _Float16* kr = Ks + (kt * 16 + l16) * AST;
        half8 kf0 = *(const half8*)(kr + quad * 8);
        half8 kf1 = *(const half8*)(kr + 32 + quad * 8);
        float4v a = (float4v)(0.f);
        a = __builtin_amdgcn_mfma_f32_16x16x32_f16(kf0, qf[qs][0], a, 0, 0, 0);
        a = __builtin_amdgcn_mfma_f32_16x16x32_f16(kf1, qf[qs][1], a, 0, 0, 0);
        s[kt] = a;
      }

      // per-lane online softmax (base-2) for q = l16
      float mx = fmaxf(fmaxf(fmaxf(s[0][0], s[0][1]), fmaxf(s[0][2], s[0][3])),
                       fmaxf(fmaxf(s[1][0], s[1][1]), fmaxf(s[1][2], s[1][3])));
      mx = fmaxf(mx, fmaxf(fmaxf(fmaxf(s[2][0], s[2][1]), fmaxf(s[2][2], s[2][3])),
                           fmaxf(fmaxf(s[3][0], s[3][1]), fmaxf(s[3][2], s[3][3]))));
      mx = fmaxf(mx, __shfl_xor(mx, 16, 64));
      mx = fmaxf(mx, __shfl_xor(mx, 32, 64));

      // defer-rescale: only rescale when some q-row's max grew by > 8 (log2)
      if (!__all(mx <= m_s[qs] + 8.0f)) {
        const float mn = fmaxf(m_s[qs], mx);
        const float alpha = exp2f(m_s[qs] - mn);
        m_s[qs] = mn;
        l_s[qs] *= alpha;
        float ab[4];
#pragma unroll
        for (int r = 0; r < 4; ++r) ab[r] = __shfl(alpha, quad * 4 + r, 64);
#pragma unroll
        for (int nt = 0; nt < 4; ++nt)
#pragma unroll
          for (int r = 0; r < 4; ++r) acc[qs][nt][r] *= ab[r];
      }

      _Float16* pw = Ps[wave][qs];
      float sum = 0.0f;
#pragma unroll
      for (int kt = 0; kt < 4; ++kt) {
        const float p0 = exp2f(s[kt][0] - m_s[qs]);
        const float p1 = exp2f(s[kt][1] - m_s[qs]);
        const float p2 = exp2f(s[kt][2] - m_s[qs]);
        const float p3 = exp2f(s[kt][3] - m_s[qs]);
        sum += (p0 + p1) + (p2 + p3);
        union { fp16x2 h2[2]; uint2 u; } pk;
        pk.h2[0] = __builtin_amdgcn_cvt_pkrtz(p0, p1);
        pk.h2[1] = __builtin_amdgcn_cvt_pkrtz(p2, p3);
        *(uint2*)(pw + l16 * PST + kt * 16 + quad * 4) = pk.u;
      }
      sum += __shfl_xor(sum, 16, 64);
      sum += __shfl_xor(sum, 32, 64);
      l_s[qs] += sum;

      // O += P @ V
      half8 pf0 = *(const half8*)(pw + l16 * PST + quad * 8);
      half8 pf1 = *(const half8*)(pw + l16 * PST + 32 + quad * 8);
#pragma unroll
      for (int nt = 0; nt < 4; ++nt) {
        const _Float16* vr = Vs + (nt * 16 + l16) * AST;
        half8 vf0 = *(const half8*)(vr + quad * 8);
        half8 vf1 = *(const half8*)(vr + 32 + quad * 8);
        acc[qs][nt] = __builtin_amdgcn_mfma_f32_16x16x32_f16(pf0, vf0, acc[qs][nt], 0, 0, 0);
        acc[qs][nt] = __builtin_amdgcn_mfma_f32_16x16x32_f16(pf1, vf1, acc[qs][nt], 0, 0, 0);
      }
    }
  }

#pragma unroll
  for (int qs = 0; qs < 2; ++qs) {
    const float inv = 1.0f / l_s[qs];
    float ib[4];
#pragma unroll
    for (int r = 0; r < 4; ++r) ib[r] = __shfl(inv, quad * 4 + r, 64);
#pragma unroll
    for (int nt = 0; nt < 4; ++nt) {
#pragma unroll
      for (int r = 0; r < 4; ++r) {
        const int m = q0 + wave * 32 + qs * 16 + quad * 4 + r;
        ao[(size_t)(b * 1024 + m) * 768 + h * 64 + nt * 16 + l16] =
            f2bf(acc[qs][nt][r] * ib[r]);
      }
    }
  }
}

// ---------- out-proj GEMM + bias + residual -> x2 (f32), 128x64 tiles ----------
__global__ void gemm_outproj_kernel(const unsigned short* __restrict__ ao,
                                    const unsigned short* __restrict__ woutt,
                                    const float* __restrict__ b_out,
                                    const float* __restrict__ x,
                                    float* __restrict__ x2) {
  GEMM12864_PROLOGUE(12)
  gemm12864(ao, 768, woutt, 768, 768, row0, col0, As, Bs, acc);
#pragma unroll
  for (int mt = 0; mt < 2; ++mt)
#pragma unroll
    for (int nt = 0; nt < 4; ++nt) {
      const int j = col0 + nt * 16 + l16;
#pragma unroll
      for (int r = 0; r < 4; ++r) {
        const int m = row0 + wave * 32 + mt * 16 + quad * 4 + r;
        const size_t idx = (size_t)m * 768 + j;
        x2[idx] = acc[mt][nt][r] + b_out[j] + x[idx];
      }
    }
}

// ---------- MLP1 GEMM + bias + exact GELU -> h1 (bf16), 128x128 ----------
__global__ void gemm_mlp1_kernel(const unsigned short* __restrict__ h,
                                 const unsigned short* __restrict__ w1t,
                                 const float* __restrict__ b1,
                                 unsigned short* __restrict__ h1) {
  GEMM128_PROLOGUE(24)
  gemm128(h, 768, w1t, 768, 768, row0, col0, As, Bs, acc);
#pragma unroll
  for (int mt = 0; mt < 4; ++mt)
#pragma unroll
    for (int nt = 0; nt < 4; ++nt) {
      const int j = col0 + wc * 64 + nt * 16 + l16;
#pragma unroll
      for (int r = 0; r < 4; ++r) {
        const int m = row0 + wr * 64 + mt * 16 + quad * 4 + r;
        const float y = acc[mt][nt][r] + b1[j];
        h1[(size_t)m * 3072 + j] = f2bf(gelu_f(y));
      }
    }
}

// ---------- MLP2 GEMM + bias + residual -> out (f32), 128x64 tiles ----------
__global__ void gemm_mlp2_kernel(const unsigned short* __restrict__ h1,
                                 const unsigned short* __restrict__ w2t,
                                 const float* __restrict__ b2,
                                 const float* __restrict__ x2,
                                 float* __restrict__ out) {
  GEMM12864_PROLOGUE(12)
  gemm12864(h1, 3072, w2t, 3072, 3072, row0, col0, As, Bs, acc);
#pragma unroll
  for (int mt = 0; mt < 2; ++mt)
#pragma unroll
    for (int nt = 0; nt < 4; ++nt) {
      const int j = col0 + nt * 16 + l16;
#pragma unroll
      for (int r = 0; r < 4; ++r) {
        const int m = row0 + wave * 32 + mt * 16 + quad * 4 + r;
        const size_t idx = (size_t)m * 768 + j;
        out[idx] = acc[mt][nt][r] + b2[j] + x2[idx];
      }
    }
}

// ---------- launch ----------
extern "C" void kernel_launch(void* const* d_in, const int* in_sizes, int n_in,
                              void* d_out, int out_size, void* d_ws, size_t ws_size,
                              hipStream_t stream) {
  const float* x       = (const float*)d_in[0];
  const float* q_extra = (const float*)d_in[1];
  const float* ln1_g   = (const float*)d_in[2];
  const float* ln1_b   = (const float*)d_in[3];
  const float* w_kv    = (const float*)d_in[4];
  const float* w_out   = (const float*)d_in[5];
  const float* b_out   = (const float*)d_in[6];
  const float* ln2_g   = (const float*)d_in[7];
  const float* ln2_b   = (const float*)d_in[8];
  const float* w1      = (const float*)d_in[9];
  const float* b1      = (const float*)d_in[10];
  const float* w2      = (const float*)d_in[11];
  const float* b2      = (const float*)d_in[12];
  float* out = (float*)d_out;

  char* ws = (char*)d_ws;
  unsigned short* xn    = (unsigned short*)(ws);
  _Float16*       kbuf  = (_Float16*)(ws + 12582912);
  _Float16*       vtbuf = (_Float16*)(ws + 25165824);
  unsigned short* ao    = (unsigned short*)(ws + 37748736);
  float*          x2    = (float*)(ws + 50331648);
  unsigned short* h1    = (unsigned short*)(ws + 75497472);
  unsigned short* hbuf  = xn;   // xn dead after kv GEMM
  unsigned short* wkvt  = ao;                          // dead before attn writes ao
  unsigned short* woutt = h1;                          // dead before mlp1 writes h1
  unsigned short* w1t   = (unsigned short*)kbuf;       // kbuf dead after attn
  unsigned short* w2t   = (unsigned short*)vtbuf;      // vtbuf dead after attn

  ln_kernel<<<2048, 256, 0, stream>>>(x, ln1_g, ln1_b, xn);
  wtrans_kernel<<<dim3(48, 24), 256, 0, stream>>>(w_kv, wkvt, 768, 1536);
  wtrans_kernel<<<dim3(24, 24), 256, 0, stream>>>(w_out, woutt, 768, 768);
  gemm_kv_kernel<<<768, 256, 0, stream>>>(xn, wkvt, kbuf, vtbuf);
  attn_kernel<<<768, 256, 0, stream>>>(q_extra, kbuf, vtbuf, ao);
  wtrans_kernel<<<dim3(96, 24), 256, 0, stream>>>(w1, w1t, 768, 3072);
  wtrans_kernel<<<dim3(24, 96), 256, 0, stream>>>(w2, w2t, 3072, 768);
  gemm_outproj_kernel<<<768, 256, 0, stream>>>(ao, woutt, b_out, x, x2);
  ln_kernel<<<2048, 256, 0, stream>>>(x2, ln2_g, ln2_b, hbuf);
  gemm_mlp1_kernel<<<1536, 256, 0, stream>>>(hbuf, w1t, b1, h1);
  gemm_mlp2_kernel<<<768, 256, 0, stream>>>(h1, w2t, b2, x2, out);
}